// Round 2
// 113.141 us; speedup vs baseline: 1.0087x; 1.0087x over previous
//
#include <hip/hip_runtime.h>
#include <hip/hip_bf16.h>

#define B_    2
#define SQ_   2048
#define SK_   2048
#define NH_   16
#define DH_   64
#define WIN_  256
#define NEG_  -30000.0f

typedef __bf16 bf16_t;
typedef bf16_t bf16x8 __attribute__((ext_vector_type(8)));
typedef bf16_t bf16x4 __attribute__((ext_vector_type(4)));
typedef float  f32x4  __attribute__((ext_vector_type(4)));
typedef short  s16x4  __attribute__((ext_vector_type(4)));

// 64-element rows + 8 pad = 144 B stride: b128/b64 accesses stay 16B-aligned
#define KSTRIDE 72
#define VSTRIDE 72
#define PSTRIDE 72

#if defined(__has_builtin)
#if __has_builtin(__builtin_amdgcn_mfma_f32_16x16x16bf16_1k)
#define HAVE_MFMA16 1
#endif
#endif

__global__ __launch_bounds__(512, 4)
void fa_fwd(const float* __restrict__ qg, const float* __restrict__ kvg,
            float* __restrict__ outg) {
  const int tid  = threadIdx.x;
  const int wid  = tid >> 6;      // 0..7, each wave owns 16 q-rows
  const int lane = tid & 63;
  const int quad = lane >> 4;
  const int li   = lane & 15;

  const int bid = blockIdx.x;
  const int qb  = bid >> 5;   // 16 q-blocks of 128 rows
  const int bh  = bid & 31;   // same bh -> same XCD (kv L2 locality)
  const int b   = bh >> 4;
  const int h   = bh & 15;

  const int q0b = qb * 128;
  const int q0  = q0b + wid * 16;

  __shared__ __align__(16) bf16_t sK [2][64 * KSTRIDE];   // K tiles [key][d]
  __shared__ __align__(16) bf16_t sVT[2][64 * VSTRIDE];   // V^T tiles [d][key^swz]
#ifndef HAVE_MFMA16
  __shared__ __align__(16) bf16_t sP [8][16 * PSTRIDE];   // per-wave P [qrow][key]
  bf16_t* pl = sP[wid];
#endif

  // ---- Q fragments (16 rows), scale * log2(e) folded ----
  const float qscale = 0.125f * 1.44269504088896340736f;
  const float* qrow = qg + ((size_t)((b * SQ_ + q0 + li) * NH_ + h)) * DH_;
  bf16x8 qfrag[2];
#pragma unroll
  for (int c = 0; c < 2; ++c) {
    f32x4 a0 = *(const f32x4*)(qrow + c * 32 + quad * 8);
    f32x4 a1 = *(const f32x4*)(qrow + c * 32 + quad * 8 + 4);
#pragma unroll
    for (int i = 0; i < 4; ++i) {
      qfrag[c][i]     = (bf16_t)(a0[i] * qscale);
      qfrag[c][i + 4] = (bf16_t)(a1[i] * qscale);
    }
  }

  f32x4 oacc[4];
#pragma unroll
  for (int t = 0; t < 4; ++t) { f32x4 z = {0.f, 0.f, 0.f, 0.f}; oacc[t] = z; }
  float m = NEG_, l = 0.f;

  // block-uniform 64-aligned key range
  int klo = q0b - WIN_; if (klo < 0) klo = 0;
  int khi = q0b + 127 + WIN_ + 1; if (khi > SK_) khi = SK_;

  const float* kbase = kvg + (size_t)b * SK_ * 2 * NH_ * DH_ + (size_t)h * DH_;
  const float* vbase = kbase + NH_ * DH_;
  const size_t krow_stride = 2 * NH_ * DH_;

  // staging: 512 threads cover 64 keys x 64 d (8 floats each of K and V)
  const int skey = tid >> 3;        // 0..63
  const int sd0  = (tid & 7) * 8;   // 0,8,...,56
  // swizzled V^T column: spreads the transpose scatter across all 32 banks
  const int vcol = skey ^ (((sd0 >> 3) & 7) << 3);

  f32x4 ka[2], va[2];
  // ---- prologue: load + stage tile 0 into buf 0 ----
  {
    const float* kr = kbase + (size_t)(klo + skey) * krow_stride + sd0;
    const float* vr = vbase + (size_t)(klo + skey) * krow_stride + sd0;
    ka[0] = *(const f32x4*)kr;       ka[1] = *(const f32x4*)(kr + 4);
    va[0] = *(const f32x4*)vr;       va[1] = *(const f32x4*)(vr + 4);
  }
  {
    bf16x8 w;
#pragma unroll
    for (int i = 0; i < 4; ++i) { w[i] = (bf16_t)ka[0][i]; w[i + 4] = (bf16_t)ka[1][i]; }
    *(bf16x8*)(&sK[0][skey * KSTRIDE + sd0]) = w;
#pragma unroll
    for (int i = 0; i < 4; ++i) {
      sVT[0][(sd0 + i)     * VSTRIDE + vcol] = (bf16_t)va[0][i];
      sVT[0][(sd0 + 4 + i) * VSTRIDE + vcol] = (bf16_t)va[1][i];
    }
  }
  __syncthreads();

  int buf = 0;
  for (int kk = klo; kk < khi; kk += 64) {
    const bool nxt = (kk + 64 < khi);   // block-uniform
    // ---- issue next tile's global loads (in flight across compute) ----
    if (nxt) {
      const float* kr = kbase + (size_t)(kk + 64 + skey) * krow_stride + sd0;
      const float* vr = vbase + (size_t)(kk + 64 + skey) * krow_stride + sd0;
      ka[0] = *(const f32x4*)kr;       ka[1] = *(const f32x4*)(kr + 4);
      va[0] = *(const f32x4*)vr;       va[1] = *(const f32x4*)(vr + 4);
    }

    // ---- compute only if this tile intersects the wave's window ----
    if (kk + 63 >= q0 - WIN_ && kk <= q0 + 15 + WIN_) {
      // S^T = K . Q^T : 4 key subtiles, D=64 as two K=32 chunks
      f32x4 sc[4];
#pragma unroll
      for (int s = 0; s < 4; ++s) {
        bf16x8 kf0 = *(const bf16x8*)(&sK[buf][(s * 16 + li) * KSTRIDE + quad * 8]);
        bf16x8 kf1 = *(const bf16x8*)(&sK[buf][(s * 16 + li) * KSTRIDE + 32 + quad * 8]);
        f32x4 acc = {0.f, 0.f, 0.f, 0.f};
        acc = __builtin_amdgcn_mfma_f32_16x16x32_bf16(kf0, qfrag[0], acc, 0, 0, 0);
        acc = __builtin_amdgcn_mfma_f32_16x16x32_bf16(kf1, qfrag[1], acc, 0, 0, 0);
        sc[s] = acc;
      }
      // window mask only on boundary tiles (wave-uniform branch)
      if (kk < q0 - 241 || kk > q0 + 193) {
        const int qa = q0 + li;
#pragma unroll
        for (int s = 0; s < 4; ++s)
#pragma unroll
          for (int r = 0; r < 4; ++r) {
            int key = kk + s * 16 + quad * 4 + r;
            unsigned dd = (unsigned)(key - qa + WIN_);
            if (dd > 2u * WIN_) sc[s][r] = NEG_;
          }
      }
      // online softmax, state per q-col = li
      float tmax = NEG_;
#pragma unroll
      for (int s = 0; s < 4; ++s)
        tmax = fmaxf(tmax, fmaxf(fmaxf(sc[s][0], sc[s][1]), fmaxf(sc[s][2], sc[s][3])));
      tmax = fmaxf(tmax, __shfl_xor(tmax, 16));
      tmax = fmaxf(tmax, __shfl_xor(tmax, 32));

      // T13 defer-max: skip rescale while max growth <= 8 (log2 domain)
      const bool defer = (__all(tmax <= m + 8.0f) != 0);
      const float mnew = defer ? m : fmaxf(m, tmax);

      float psum = 0.f;
#ifdef HAVE_MFMA16
      // P stays in-lane: QK^T C-layout == 16x16x16 MFMA A-layout per key subtile
      bf16x4 pa[4];
#pragma unroll
      for (int s = 0; s < 4; ++s) {
        float p0 = exp2f(sc[s][0] - mnew);
        float p1 = exp2f(sc[s][1] - mnew);
        float p2 = exp2f(sc[s][2] - mnew);
        float p3 = exp2f(sc[s][3] - mnew);
        psum += (p0 + p1) + (p2 + p3);
        pa[s][0] = (bf16_t)p0; pa[s][1] = (bf16_t)p1;
        pa[s][2] = (bf16_t)p2; pa[s][3] = (bf16_t)p3;
      }
#else
#pragma unroll
      for (int s = 0; s < 4; ++s) {
        bf16x4 pk;
#pragma unroll
        for (int r = 0; r < 4; ++r) {
          float p = exp2f(sc[s][r] - mnew);
          psum += p;
          pk[r] = (bf16_t)p;
        }
        *(bf16x4*)(&pl[li * PSTRIDE + s * 16 + quad * 4]) = pk;
      }
#endif
      psum += __shfl_xor(psum, 16);
      psum += __shfl_xor(psum, 32);

      if (!defer) {
        const float alpha = exp2f(m - mnew);
        float al[4];
#pragma unroll
        for (int r = 0; r < 4; ++r) al[r] = __shfl(alpha, quad * 4 + r);
#pragma unroll
        for (int t = 0; t < 4; ++t) {
          oacc[t][0] *= al[0]; oacc[t][1] *= al[1];
          oacc[t][2] *= al[2]; oacc[t][3] *= al[3];
        }
        l = l * alpha + psum;
        m = mnew;
      } else {
        l += psum;
      }

#ifdef HAVE_MFMA16
      // O += P . V : K=16 MFMA per key subtile, P from registers (no transpose)
#pragma unroll
      for (int s = 0; s < 4; ++s) {
        const s16x4 pas = __builtin_bit_cast(s16x4, pa[s]);
#pragma unroll
        for (int t = 0; t < 4; ++t) {
          const int d  = 16 * t + li;
          const int c8 = ((2 * t + (li >> 3)) & 7) << 3;
          s16x4 vb = *(const s16x4*)(&sVT[buf][d * VSTRIDE + ((s * 16 + quad * 4) ^ c8)]);
          oacc[t] = __builtin_amdgcn_mfma_f32_16x16x16bf16_1k(pas, vb, oacc[t], 0, 0, 0);
        }
      }
#else
      // wave-local drain: sP round-trip is per-wave
      asm volatile("s_waitcnt lgkmcnt(0)" ::: "memory");
#pragma unroll
      for (int kc = 0; kc < 2; ++kc) {
        bf16x8 pf = *(const bf16x8*)(&pl[li * PSTRIDE + kc * 32 + quad * 8]);
#pragma unroll
        for (int t = 0; t < 4; ++t) {
          const int d = 16 * t + li;
          const int c = ((2 * t + (li >> 3)) & 7) << 3;
          bf16x8 vf = *(const bf16x8*)(&sVT[buf][d * VSTRIDE + ((kc * 32 + quad * 8) ^ c)]);
          oacc[t] = __builtin_amdgcn_mfma_f32_16x16x32_bf16(pf, vf, oacc[t], 0, 0, 0);
        }
      }
#endif
    }

    // ---- stage next tile into the other buffer ----
    if (nxt) {
      bf16x8 w;
#pragma unroll
      for (int i = 0; i < 4; ++i) { w[i] = (bf16_t)ka[0][i]; w[i + 4] = (bf16_t)ka[1][i]; }
      *(bf16x8*)(&sK[buf ^ 1][skey * KSTRIDE + sd0]) = w;
#pragma unroll
      for (int i = 0; i < 4; ++i) {
        sVT[buf ^ 1][(sd0 + i)     * VSTRIDE + vcol] = (bf16_t)va[0][i];
        sVT[buf ^ 1][(sd0 + 4 + i) * VSTRIDE + vcol] = (bf16_t)va[1][i];
      }
    }
    __syncthreads();   // the single barrier per iteration
    buf ^= 1;
  }

  // ---- epilogue ----
  float rl[4];
#pragma unroll
  for (int r = 0; r < 4; ++r) {
    float lv = __shfl(l, quad * 4 + r);
    rl[r] = 1.0f / lv;
  }
  float* orow = outg + ((size_t)((b * SQ_ + q0) * NH_ + h)) * DH_;
#pragma unroll
  for (int t = 0; t < 4; ++t)
#pragma unroll
    for (int r = 0; r < 4; ++r)
      orow[(size_t)(quad * 4 + r) * (NH_ * DH_) + 16 * t + li] = oacc[t][r] * rl[r];
}

extern "C" void kernel_launch(void* const* d_in, const int* in_sizes, int n_in,
                              void* d_out, int out_size, void* d_ws, size_t ws_size,
                              hipStream_t stream) {
  (void)in_sizes; (void)n_in; (void)out_size; (void)d_ws; (void)ws_size;
  const float* q  = (const float*)d_in[0];
  const float* kv = (const float*)d_in[1];
  float* out = (float*)d_out;
  dim3 grid(B_ * NH_ * (SQ_ / 128));  // 512 blocks x 8 waves = 16 waves/CU
  fa_fwd<<<grid, 512, 0, stream>>>(q, kv, out);
}